// Round 14
// baseline (284.505 us; speedup 1.0000x reference)
//
#include <hip/hip_runtime.h>
#include <math.h>
#include <limits.h>

// RelativeBucketedTimeAndPositionBasedBias — B=16, N=2048, NUM_BUCKETS=128
// out[b,i,j] = pos_w[N-1 + j - i] + ts_w[bucket(b,i,j)]
//   diff = ext[b,i+1] - ext[b,j]; m = max(|diff·causal|, 1)  (integer, < 2^24)
//
// VERIFIED BIT-EXACT (R12/R13, absmax=0): ref pipeline is
//   bucket = clip(trunc( RN_f32( log32(m) * RN_f32(1/0.301f) ) ), 0, 128)
// realized as bucket(m) = max{ k : T[k] <= m } over exact integer thresholds T.
//
// R14 perf: dur_us = wspoison(162) + outpoison(40) + setup + main(~76).
// Main was VALU-bound (v_log_f32 + 3 LDS gathers + ~16 VALU per causal elem).
// New causal path: clz -> etab[clz] = (base, T[base+1..3]) int4 (one b128) ->
// b = base + 3 compares -> s_tsw[b]. Equivalent to max{k: T[k]<=m} because per
// octave [2^E,2^{E+1}) bucket spans <= base..base+3 (q-span = ln2*3.3223 = 2.30,
// q monotone, base = bucket(2^E) exactly). Also pos_w window read as 16B.

#define NN 2048
#define BLOCK 256
#define NTHR 130   // thresholds T[0..129]

__global__ void build_thresholds_kernel(int* __restrict__ T) {
    const int k = blockIdx.x;              // 0..129
    __shared__ int s_min;
    if (threadIdx.x == 0) s_min = INT_MAX;
    __syncthreads();

    const float recip = (float)(1.0 / (double)0.301f);   // RN_f32(1/f32(0.301))
    const double est = exp(0.301 * (double)k);
    if (est > 2.0e9) {
        if (threadIdx.x == 0) T[k] = INT_MAX;
        return;
    }
    long long lo = (long long)floor(est) - 256;
    if (lo < 1) lo = 1;
    const long long m = lo + (long long)threadIdx.x;     // one candidate/thread
    const float lg = (float)log((double)m);              // CR f32 log of integer m
    const float q = lg * recip;                          // f32 RN multiply
    if ((int)q >= k) atomicMin(&s_min, (int)m);          // monotone predicate
    __syncthreads();
    if (threadIdx.x == 0) T[k] = s_min;
}

// etab[clz(m)] = (base, T[base+1], T[base+2], T[base+3]) where base = bucket(2^E),
// E = 31 - clz. bucket(m) = base + (m>=T[base+1]) + (m>=T[base+2]) + (m>=T[base+3]).
__global__ void build_etab_kernel(const int* __restrict__ T, int4* __restrict__ etab) {
    const int c = threadIdx.x;             // clz value 0..31
    if (c >= 32) return;
    const int E = 31 - c;
    const long long mE = 1LL << E;
    // base = max{ k in [0,129] : T[k] <= 2^E }  (T nondecreasing, T[0]=1)
    int lo = 0, hi = NTHR - 1;
    while (lo < hi) {
        const int mid = (lo + hi + 1) >> 1;
        if ((long long)T[mid] <= mE) lo = mid; else hi = mid - 1;
    }
    int4 e;
    e.x = lo;
    e.y = T[min(lo + 1, NTHR - 1)];
    e.z = T[min(lo + 2, NTHR - 1)];
    e.w = T[min(lo + 3, NTHR - 1)];
    etab[c] = e;
}

__device__ __forceinline__ float bias_elem(int t_next, int tj, int j, int i,
                                           const float* __restrict__ s_tsw,
                                           const int4* __restrict__ s_etab,
                                           float ts0, float pv) {
    if (j > i) return pv + ts0;            // non-causal: td=0 -> bucket 0
    int mi = t_next - tj;                  // >= 0 (rows sorted)
    mi = mi < 1 ? 1 : mi;                  // max(|td|, 1); mi in [1, 2^24)
    const int4 e = s_etab[__clz(mi)];      // (base, T[base+1], T[base+2], T[base+3])
    const int b = e.x + (mi >= e.y) + (mi >= e.z) + (mi >= e.w);
    return pv + s_tsw[b];
}

__global__ __launch_bounds__(BLOCK) void hstu_bias_kernel(
    const int* __restrict__ ts,       // [B, N] int32, sorted per row
    const float* __restrict__ ts_w,   // [129]
    const float* __restrict__ pos_w,  // [2N-1]
    const int4* __restrict__ etab,    // [32]
    float* __restrict__ out)          // [B, N, N]
{
    __shared__ float s_tsw[129];
    __shared__ int4 s_etab[32];
    const int tid = threadIdx.x;
    if (tid < 129) s_tsw[tid] = ts_w[tid];
    if (tid < 32) s_etab[tid] = etab[tid];
    __syncthreads();

    const int row = blockIdx.x;          // b*N + i
    const int b = row >> 11;
    const int i = row & (NN - 1);
    const int* __restrict__ ts_row = ts + b * NN;
    const int t_next = ts_row[(i < NN - 1) ? (i + 1) : (NN - 1)];  // ext[b,i+1]
    const float* __restrict__ pw = pos_w + (NN - 1 - i);           // pw[j] = pos_w[N-1+j-i]
    float4* __restrict__ out4 = (float4*)(out + (size_t)row * NN);
    const float ts0 = s_tsw[0];

#pragma unroll
    for (int it = 0; it < 2; ++it) {
        const int j4 = tid + it * BLOCK;
        const int j = j4 * 4;
        const int4 tj = *(const int4*)(ts_row + j);  // aligned 16B
        float4 pv4;                                   // pw+j is only 4B-aligned:
        __builtin_memcpy(&pv4, pw + j, 16);           // emits dwordx4 (align-4 ok)

        float4 r;
        r.x = bias_elem(t_next, tj.x, j + 0, i, s_tsw, s_etab, ts0, pv4.x);
        r.y = bias_elem(t_next, tj.y, j + 1, i, s_tsw, s_etab, ts0, pv4.y);
        r.z = bias_elem(t_next, tj.z, j + 2, i, s_tsw, s_etab, ts0, pv4.z);
        r.w = bias_elem(t_next, tj.w, j + 3, i, s_tsw, s_etab, ts0, pv4.w);
        out4[j4] = r;
    }
}

extern "C" void kernel_launch(void* const* d_in, const int* in_sizes, int n_in,
                              void* d_out, int out_size, void* d_ws, size_t ws_size,
                              hipStream_t stream) {
    const int* ts = (const int*)d_in[0];        // all_timestamps [16,2048]
    const float* ts_w = (const float*)d_in[1];  // [129]
    const float* pos_w = (const float*)d_in[2]; // [4095]
    float* out = (float*)d_out;                 // [16,2048,2048] f32
    int* T = (int*)d_ws;                        // [130] at ws+0
    int4* etab = (int4*)((char*)d_ws + 1024);   // [32] at ws+1024 (16B aligned)

    build_thresholds_kernel<<<dim3(NTHR), dim3(512), 0, stream>>>(T);
    build_etab_kernel<<<dim3(1), dim3(32), 0, stream>>>(T, etab);

    const int B = 16;
    hstu_bias_kernel<<<dim3(B * NN), dim3(BLOCK), 0, stream>>>(ts, ts_w, pos_w, etab, out);
}

// Round 15
// 272.090 us; speedup vs baseline: 1.0456x; 1.0456x over previous
//
#include <hip/hip_runtime.h>
#include <math.h>
#include <limits.h>

// RelativeBucketedTimeAndPositionBasedBias — B=16, N=2048, NUM_BUCKETS=128
// out[b,i,j] = pos_w[N-1 + j - i] + ts_w[bucket(b,i,j)]
//   diff = ext[b,i+1] - ext[b,j]; m = max(|diff·causal|, 1)  (integer, < 2^24)
//
// VERIFIED BIT-EXACT (R12-R14, absmax=0): ref pipeline is
//   bucket = clip(trunc( RN_f32( log32(m) * RN_f32(1/0.301f) ) ), 0, 128)
// realized as bucket(m) = max{ k : T[k] <= m } via exact integer thresholds T
// and per-octave etab: bucket = base(clz) + 3 compares. DO NOT alter.
//
// R15 perf: R13 vs R14 showed main (~76 us vs 41 us write floor) is ALU-path
// insensitive -> latency/pipeline-bound: 32768 tiny blocks, 2 stores/thread,
// staging+sync latency exposed per block. Restructure: 2048 persistent blocks
// x 16 rows. ts columns identical across a block's rows -> 2 int4 registers;
// staging amortized 16x; 32 stores/thread (deep store stream, row-level ILP).
// pos_w stays global/L1 (LDS copy would 8-way bank-conflict on lane-stride-4).

#define NN 2048
#define BLOCK 256
#define ROWS 16
#define NTHR 130   // thresholds T[0..129]

__global__ void build_thresholds_kernel(int* __restrict__ T) {
    const int k = blockIdx.x;              // 0..129
    __shared__ int s_min;
    if (threadIdx.x == 0) s_min = INT_MAX;
    __syncthreads();

    const float recip = (float)(1.0 / (double)0.301f);   // RN_f32(1/f32(0.301))
    const double est = exp(0.301 * (double)k);
    if (est > 2.0e9) {
        if (threadIdx.x == 0) T[k] = INT_MAX;
        return;
    }
    long long lo = (long long)floor(est) - 256;
    if (lo < 1) lo = 1;
    const long long m = lo + (long long)threadIdx.x;     // one candidate/thread
    const float lg = (float)log((double)m);              // CR f32 log of integer m
    const float q = lg * recip;                          // f32 RN multiply
    if ((int)q >= k) atomicMin(&s_min, (int)m);          // monotone predicate
    __syncthreads();
    if (threadIdx.x == 0) T[k] = s_min;
}

// etab[clz(m)] = (base, T[base+1], T[base+2], T[base+3]), base = bucket(2^(31-clz)).
__global__ void build_etab_kernel(const int* __restrict__ T, int4* __restrict__ etab) {
    const int c = threadIdx.x;             // clz value 0..31
    if (c >= 32) return;
    const long long mE = 1LL << (31 - c);
    int lo = 0, hi = NTHR - 1;             // base = max{k: T[k] <= 2^E}
    while (lo < hi) {
        const int mid = (lo + hi + 1) >> 1;
        if ((long long)T[mid] <= mE) lo = mid; else hi = mid - 1;
    }
    int4 e;
    e.x = lo;
    e.y = T[min(lo + 1, NTHR - 1)];
    e.z = T[min(lo + 2, NTHR - 1)];
    e.w = T[min(lo + 3, NTHR - 1)];
    etab[c] = e;
}

__device__ __forceinline__ float bias_elem(int t_next, int tj, int j, int i,
                                           const float* __restrict__ s_tsw,
                                           const int4* __restrict__ s_etab,
                                           float ts0, float pv) {
    if (j > i) return pv + ts0;            // non-causal: td=0 -> bucket 0
    int mi = t_next - tj;                  // >= 0 (rows sorted)
    mi = mi < 1 ? 1 : mi;                  // max(|td|, 1); mi in [1, 2^24)
    const int4 e = s_etab[__clz(mi)];      // mostly-broadcast LDS b128
    const int b = e.x + (mi >= e.y) + (mi >= e.z) + (mi >= e.w);
    return pv + s_tsw[b];
}

__global__ __launch_bounds__(BLOCK) void hstu_bias_kernel(
    const int* __restrict__ ts,       // [B, N] int32, sorted per row
    const float* __restrict__ ts_w,   // [129]
    const float* __restrict__ pos_w,  // [2N-1]
    const int4* __restrict__ etab,    // [32]
    float* __restrict__ out)          // [B, N, N]
{
    __shared__ float s_tsw[129];
    __shared__ int4 s_etab[32];
    const int tid = threadIdx.x;
    if (tid < 129) s_tsw[tid] = ts_w[tid];
    if (tid < 32) s_etab[tid] = etab[tid];

    const int grp = blockIdx.x;          // 0..2047
    const int b = grp >> 7;              // /128
    const int i0 = (grp & 127) << 4;     // *ROWS
    const int* __restrict__ ts_row = ts + b * NN;

    // ts columns are the same for all ROWS rows of this block: register-cache.
    const int j_0 = tid * 4;
    const int j_1 = tid * 4 + 1024;
    const int4 tj0 = *(const int4*)(ts_row + j_0);   // aligned 16B
    const int4 tj1 = *(const int4*)(ts_row + j_1);

    __syncthreads();
    const float ts0 = s_tsw[0];
    float* __restrict__ out_base = out + (size_t)(b * NN + i0) * NN;

#pragma unroll 4
    for (int r = 0; r < ROWS; ++r) {
        const int i = i0 + r;
        const int t_next = ts_row[(i < NN - 1) ? (i + 1) : (NN - 1)];  // uniform s_load
        const float* __restrict__ pw = pos_w + (NN - 1 - i);           // pw[j]
        float4* __restrict__ out4 = (float4*)(out_base + (size_t)r * NN);

        float4 pva, pvb;                         // 4B-aligned 16B loads (L1-hit)
        __builtin_memcpy(&pva, pw + j_0, 16);
        __builtin_memcpy(&pvb, pw + j_1, 16);

        float4 ra, rb;
        ra.x = bias_elem(t_next, tj0.x, j_0 + 0, i, s_tsw, s_etab, ts0, pva.x);
        ra.y = bias_elem(t_next, tj0.y, j_0 + 1, i, s_tsw, s_etab, ts0, pva.y);
        ra.z = bias_elem(t_next, tj0.z, j_0 + 2, i, s_tsw, s_etab, ts0, pva.z);
        ra.w = bias_elem(t_next, tj0.w, j_0 + 3, i, s_tsw, s_etab, ts0, pva.w);
        rb.x = bias_elem(t_next, tj1.x, j_1 + 0, i, s_tsw, s_etab, ts0, pvb.x);
        rb.y = bias_elem(t_next, tj1.y, j_1 + 1, i, s_tsw, s_etab, ts0, pvb.y);
        rb.z = bias_elem(t_next, tj1.z, j_1 + 2, i, s_tsw, s_etab, ts0, pvb.z);
        rb.w = bias_elem(t_next, tj1.w, j_1 + 3, i, s_tsw, s_etab, ts0, pvb.w);

        out4[tid] = ra;
        out4[tid + 256] = rb;
    }
}

extern "C" void kernel_launch(void* const* d_in, const int* in_sizes, int n_in,
                              void* d_out, int out_size, void* d_ws, size_t ws_size,
                              hipStream_t stream) {
    const int* ts = (const int*)d_in[0];        // all_timestamps [16,2048]
    const float* ts_w = (const float*)d_in[1];  // [129]
    const float* pos_w = (const float*)d_in[2]; // [4095]
    float* out = (float*)d_out;                 // [16,2048,2048] f32
    int* T = (int*)d_ws;                        // [130] at ws+0
    int4* etab = (int4*)((char*)d_ws + 1024);   // [32] at ws+1024 (16B aligned)

    build_thresholds_kernel<<<dim3(NTHR), dim3(512), 0, stream>>>(T);
    build_etab_kernel<<<dim3(1), dim3(32), 0, stream>>>(T, etab);

    const int B = 16;
    hstu_bias_kernel<<<dim3(B * NN / ROWS), dim3(BLOCK), 0, stream>>>(ts, ts_w, pos_w, etab, out);
}